// Round 6
// baseline (13633.731 us; speedup 1.0000x reference)
//
#include <hip/hip_runtime.h>

#define T_STEPS 4096
#define N_RES   2048
#define N_IN    64
#define N_OUT   64
#define LEAK    0.3f
#define NOISE_S 0.01f

#define NWG     128      // reservoir WGs: 16 rows each
#define RPW     16       // rows per WG
#define RPWAVE  4        // rows per wave (= one 16B poll group)

typedef unsigned int uint32x4 __attribute__((ext_vector_type(4)));

// ---------------------------------------------------------------------------
// Kernel 1: it[t][n] = dot(u[t,:], W_in[n,:]) + 0.01*noise[t][n]
// ---------------------------------------------------------------------------
__global__ __launch_bounds__(256) void input_terms_kernel(
    const float* __restrict__ u, const float* __restrict__ noise,
    const float* __restrict__ W_in, float* __restrict__ it) {
  const int t = blockIdx.x;
  const int tid = threadIdx.x;
  __shared__ float su[N_IN];
  if (tid < N_IN) su[tid] = u[(size_t)t * N_IN + tid];
  __syncthreads();
  #pragma unroll
  for (int k = 0; k < N_RES / 256; ++k) {
    const int n = tid + 256 * k;
    const float4* wr = reinterpret_cast<const float4*>(W_in + (size_t)n * N_IN);
    float acc = 0.f;
    #pragma unroll
    for (int j = 0; j < N_IN / 4; ++j) {
      float4 w4 = wr[j];
      acc = fmaf(w4.x, su[4 * j + 0], acc);
      acc = fmaf(w4.y, su[4 * j + 1], acc);
      acc = fmaf(w4.z, su[4 * j + 2], acc);
      acc = fmaf(w4.w, su[4 * j + 3], acc);
    }
    it[(size_t)t * N_RES + n] = acc + NOISE_S * noise[(size_t)t * N_RES + n];
  }
}

// ---------------------------------------------------------------------------
// Kernel 2: persistent recurrence, 4B tagged state, per-wave immediate emit.
//
// 128 WGs x 256 threads (1/CU). WG w owns rows [16w,16w+16); wave v owns the
// 4 adjacent rows 16w+4v.. (= exactly one 16B poll group, so a group becomes
// fresh with ONE tagged dwordx4 store — atomic flip, no partial groups).
//
// State word = fp32 bits, low 2 mantissa bits = step&3 (skew <= 2 steps =>
// mod-4 disambiguates; <=3 ulp perturbation). Per step, per thread: ONE
// __syncthreads; ls is double-buffered in LDS so the poll for s_{t+1} fills
// the buffer the current compute is NOT reading.
//
// Critical path per step: butterfly -> 4-lane tanh -> 3 shuffles -> lane-0
// tagged store (sc0 sc1, straight to coherence point) -> consumer poll
// (2 coalesced dwordx4 loads/thread) -> LDS fill -> sync.
// ---------------------------------------------------------------------------
__global__ __launch_bounds__(256, 1) void reservoir_kernel(
    const float* __restrict__ W, float* __restrict__ it,
    unsigned int* sbuf) {
  const int wg = blockIdx.x;
  const int tid = threadIdx.x;
  const int wave = tid >> 6;
  const int lane = tid & 63;
  const int R = wg * RPW;
  const int r0 = R + wave * RPWAVE;   // this wave's 4 rows

  __shared__ float Wl[RPW * N_RES];   // 128 KB
  __shared__ float ls[2][N_RES];      //  16 KB

  // Stage this WG's 16 W rows into LDS once (coalesced float4).
  {
    const float4* Wg = reinterpret_cast<const float4*>(W + (size_t)R * N_RES);
    float4* Wd = reinterpret_cast<float4*>(Wl);
    #pragma unroll
    for (int k = 0; k < RPW * N_RES / 4 / 256; ++k)
      Wd[tid + 256 * k] = Wg[tid + 256 * k];
  }

  // Prefetch it[0] for this wave's rows (overlaps prologue poll).
  float itv = 0.f;
  if (lane < RPWAVE) itv = it[r0 + lane];

  // Prologue: poll s_0 (memset zeros carry tag 0 -> immediate) into ls[0].
  {
    const uint32x4* pa = reinterpret_cast<const uint32x4*>(sbuf) + tid;
    const uint32x4* pb = pa + 256;
    uint32x4* dsta = reinterpret_cast<uint32x4*>(&ls[0][0]) + tid;
    uint32x4* dstb = dsta + 256;
    unsigned int need = 3u;
    while (need) {
      uint32x4 va, vb;
      asm volatile(
          "global_load_dwordx4 %0, %2, off sc0 sc1\n\t"
          "global_load_dwordx4 %1, %3, off sc0 sc1\n\t"
          "s_waitcnt vmcnt(0)"
          : "=&v"(va), "=&v"(vb) : "v"(pa), "v"(pb) : "memory");
      if ((need & 1u) &&
          (((va[0] | va[1] | va[2] | va[3]) & 3u) == 0u)) { *dsta = va; need &= ~1u; }
      if ((need & 2u) &&
          (((vb[0] | vb[1] | vb[2] | vb[3]) & 3u) == 0u)) { *dstb = vb; need &= ~2u; }
      if (need) __builtin_amdgcn_s_sleep(1);
    }
  }
  __syncthreads();

  for (unsigned int t = 0; t < T_STEPS; ++t) {
    const float* cur = ls[t & 1];
    float* nxt = ls[(t + 1) & 1];
    unsigned int* swb = sbuf + ((t + 1) & 1) * N_RES;

    // ---- 4 dot products per wave (conflict-free float4 LDS reads) ----
    const float4* S4 = reinterpret_cast<const float4*>(cur);
    const float4* W0 = reinterpret_cast<const float4*>(Wl + (size_t)(RPWAVE * wave + 0) * N_RES);
    const float4* W1 = reinterpret_cast<const float4*>(Wl + (size_t)(RPWAVE * wave + 1) * N_RES);
    const float4* W2 = reinterpret_cast<const float4*>(Wl + (size_t)(RPWAVE * wave + 2) * N_RES);
    const float4* W3 = reinterpret_cast<const float4*>(Wl + (size_t)(RPWAVE * wave + 3) * N_RES);
    float a0 = 0.f, a1 = 0.f, a2 = 0.f, a3 = 0.f;
    #pragma unroll
    for (int j = 0; j < N_RES / 4 / 64; ++j) {
      const float4 s4 = S4[lane + 64 * j];
      const float4 x0 = W0[lane + 64 * j];
      const float4 x1 = W1[lane + 64 * j];
      const float4 x2 = W2[lane + 64 * j];
      const float4 x3 = W3[lane + 64 * j];
      a0 = fmaf(x0.x, s4.x, a0); a0 = fmaf(x0.y, s4.y, a0);
      a0 = fmaf(x0.z, s4.z, a0); a0 = fmaf(x0.w, s4.w, a0);
      a1 = fmaf(x1.x, s4.x, a1); a1 = fmaf(x1.y, s4.y, a1);
      a1 = fmaf(x1.z, s4.z, a1); a1 = fmaf(x1.w, s4.w, a1);
      a2 = fmaf(x2.x, s4.x, a2); a2 = fmaf(x2.y, s4.y, a2);
      a2 = fmaf(x2.z, s4.z, a2); a2 = fmaf(x2.w, s4.w, a2);
      a3 = fmaf(x3.x, s4.x, a3); a3 = fmaf(x3.y, s4.y, a3);
      a3 = fmaf(x3.z, s4.z, a3); a3 = fmaf(x3.w, s4.w, a3);
    }
    #pragma unroll
    for (int off = 32; off > 0; off >>= 1) {
      a0 += __shfl_xor(a0, off);
      a1 += __shfl_xor(a1, off);
      a2 += __shfl_xor(a2, off);
      a3 += __shfl_xor(a3, off);
    }

    // ---- lanes 0..3: finalize own row in parallel ----
    float snew = 0.f;
    if (lane < RPWAVE) {
      const float a = (lane == 0) ? a0 : (lane == 1) ? a1 : (lane == 2) ? a2 : a3;
      const float h = tanhf(itv + a);
      const float sold = cur[r0 + lane];
      snew = (1.0f - LEAK) * sold + LEAK * h;
      it[(size_t)t * N_RES + r0 + lane] = snew;  // record state for readout
    }

    // ---- pack 4 rows -> one tagged dwordx4, lane 0 emits immediately ----
    {
      const unsigned int tg = (t + 1) & 3u;
      uint32x4 pk;
      pk[0] = (__float_as_uint(__shfl(snew, 0)) & ~3u) | tg;
      pk[1] = (__float_as_uint(__shfl(snew, 1)) & ~3u) | tg;
      pk[2] = (__float_as_uint(__shfl(snew, 2)) & ~3u) | tg;
      pk[3] = (__float_as_uint(__shfl(snew, 3)) & ~3u) | tg;
      if (lane == 0) {
        uint32x4* dst = reinterpret_cast<uint32x4*>(swb) + (r0 >> 2);
        asm volatile("global_store_dwordx4 %0, %1, off sc0 sc1"
                     :: "v"(dst), "v"(pk) : "memory");
      }
    }

    if (t + 1 < T_STEPS) {
      // Prefetch it[t+1] (own rows; we only overwrite it[t+1] during step
      // t+1 after consuming this register) — hides HBM latency under poll.
      if (lane < RPWAVE) itv = it[(size_t)(t + 1) * N_RES + r0 + lane];

      // ---- poll s_{t+1} into the other LDS buffer ----
      const unsigned int tag = (t + 1) & 3u;
      const uint32x4* pa = reinterpret_cast<const uint32x4*>(swb) + tid;
      const uint32x4* pb = pa + 256;
      uint32x4* dsta = reinterpret_cast<uint32x4*>(nxt) + tid;
      uint32x4* dstb = dsta + 256;
      unsigned int need = 3u;
      for (;;) {
        uint32x4 va, vb;
        if (need == 3u) {
          asm volatile(
              "global_load_dwordx4 %0, %2, off sc0 sc1\n\t"
              "global_load_dwordx4 %1, %3, off sc0 sc1\n\t"
              "s_waitcnt vmcnt(0)"
              : "=&v"(va), "=&v"(vb) : "v"(pa), "v"(pb) : "memory");
          if ((((va[0] ^ tag) | (va[1] ^ tag) | (va[2] ^ tag) | (va[3] ^ tag)) & 3u) == 0u) {
            *dsta = va; need &= ~1u;
          }
          if ((((vb[0] ^ tag) | (vb[1] ^ tag) | (vb[2] ^ tag) | (vb[3] ^ tag)) & 3u) == 0u) {
            *dstb = vb; need &= ~2u;
          }
        } else if (need == 1u) {
          asm volatile(
              "global_load_dwordx4 %0, %1, off sc0 sc1\n\t"
              "s_waitcnt vmcnt(0)"
              : "=&v"(va) : "v"(pa) : "memory");
          if ((((va[0] ^ tag) | (va[1] ^ tag) | (va[2] ^ tag) | (va[3] ^ tag)) & 3u) == 0u) {
            *dsta = va; need = 0u;
          }
        } else {
          asm volatile(
              "global_load_dwordx4 %0, %1, off sc0 sc1\n\t"
              "s_waitcnt vmcnt(0)"
              : "=&v"(vb) : "v"(pb) : "memory");
          if ((((vb[0] ^ tag) | (vb[1] ^ tag) | (vb[2] ^ tag) | (vb[3] ^ tag)) & 3u) == 0u) {
            *dstb = vb; need = 0u;
          }
        }
        if (!need) break;
        __builtin_amdgcn_s_sleep(1);
      }
    }
    __syncthreads();  // nxt filled; also WAR guard for cur (rewritten at t+2)
  }
}

// ---------------------------------------------------------------------------
// Kernel 3: out[t][o] = dot(states[t,:], rw[o,:]) + rb[o]
// ---------------------------------------------------------------------------
__global__ __launch_bounds__(256) void readout_kernel(
    const float* __restrict__ states, const float* __restrict__ rw,
    const float* __restrict__ rb, float* __restrict__ out) {
  const int t = blockIdx.x;
  const int tid = threadIdx.x;
  const int o = tid & 63;
  const int q = tid >> 6;  // 0..3
  __shared__ float ss[N_RES];
  #pragma unroll
  for (int k = 0; k < N_RES / 256; ++k)
    ss[tid + 256 * k] = states[(size_t)t * N_RES + tid + 256 * k];
  __syncthreads();

  const float4* r4 = reinterpret_cast<const float4*>(rw + (size_t)o * N_RES + q * 512);
  float acc = 0.f;
  #pragma unroll 8
  for (int j = 0; j < 128; ++j) {
    float4 w4 = r4[j];
    const int base = q * 512 + 4 * j;
    acc = fmaf(w4.x, ss[base + 0], acc);
    acc = fmaf(w4.y, ss[base + 1], acc);
    acc = fmaf(w4.z, ss[base + 2], acc);
    acc = fmaf(w4.w, ss[base + 3], acc);
  }
  __shared__ float red[256];
  red[tid] = acc;
  __syncthreads();
  if (tid < 64) {
    float v = red[tid] + red[tid + 64] + red[tid + 128] + red[tid + 192];
    out[(size_t)t * N_OUT + tid] = v + rb[tid];
  }
}

// ---------------------------------------------------------------------------
extern "C" void kernel_launch(void* const* d_in, const int* in_sizes, int n_in,
                              void* d_out, int out_size, void* d_ws, size_t ws_size,
                              hipStream_t stream) {
  const float* u     = (const float*)d_in[0];  // [4096, 64]
  const float* noise = (const float*)d_in[1];  // [4096, 2048]
  const float* W_in  = (const float*)d_in[2];  // [2048, 64]
  const float* W     = (const float*)d_in[3];  // [2048, 2048]
  const float* rw    = (const float*)d_in[4];  // [64, 2048]
  const float* rb    = (const float*)d_in[5];  // [64]
  float* out = (float*)d_out;                  // [4096, 64]

  float* it = (float*)d_ws;  // 32 MB: input terms, overwritten with states
  unsigned int* sbuf =
      (unsigned int*)((char*)d_ws + (size_t)T_STEPS * N_RES * sizeof(float));

  // Zero both tagged state buffers every call (tag 0 == initial zero state;
  // ws is not re-poisoned between replays). 2 * 2048 * 4B = 16 KB.
  hipMemsetAsync(sbuf, 0, 2 * N_RES * sizeof(unsigned int), stream);

  input_terms_kernel<<<T_STEPS, 256, 0, stream>>>(u, noise, W_in, it);

  void* args[] = {(void*)&W, (void*)&it, (void*)&sbuf};
  hipLaunchCooperativeKernel((void*)reservoir_kernel, dim3(NWG), dim3(256),
                             args, 0, stream);

  readout_kernel<<<T_STEPS, 256, 0, stream>>>(it, rw, rb, out);
}

// Round 7
// 13107.903 us; speedup vs baseline: 1.0401x; 1.0401x over previous
//
#include <hip/hip_runtime.h>

#define T_STEPS 4096
#define N_RES   2048
#define N_IN    64
#define N_OUT   64
#define LEAK    0.3f
#define NOISE_S 0.01f

#define NWG      128     // reservoir WGs (1 per CU on half the chip)
#define RPW      16      // rows per WG
#define RPWAVE   4       // rows per compute wave (= one 16B poll group)
#define NTHREADS 320     // 4 compute waves + 1 dedicated poll wave

typedef unsigned int uint32x4 __attribute__((ext_vector_type(4)));

// ---------------------------------------------------------------------------
// Kernel 1: it[t][n] = dot(u[t,:], W_in[n,:]) + 0.01*noise[t][n]
// ---------------------------------------------------------------------------
__global__ __launch_bounds__(256) void input_terms_kernel(
    const float* __restrict__ u, const float* __restrict__ noise,
    const float* __restrict__ W_in, float* __restrict__ it) {
  const int t = blockIdx.x;
  const int tid = threadIdx.x;
  __shared__ float su[N_IN];
  if (tid < N_IN) su[tid] = u[(size_t)t * N_IN + tid];
  __syncthreads();
  #pragma unroll
  for (int k = 0; k < N_RES / 256; ++k) {
    const int n = tid + 256 * k;
    const float4* wr = reinterpret_cast<const float4*>(W_in + (size_t)n * N_IN);
    float acc = 0.f;
    #pragma unroll
    for (int j = 0; j < N_IN / 4; ++j) {
      float4 w4 = wr[j];
      acc = fmaf(w4.x, su[4 * j + 0], acc);
      acc = fmaf(w4.y, su[4 * j + 1], acc);
      acc = fmaf(w4.z, su[4 * j + 2], acc);
      acc = fmaf(w4.w, su[4 * j + 3], acc);
    }
    it[(size_t)t * N_RES + n] = acc + NOISE_S * noise[(size_t)t * N_RES + n];
  }
}

// ---------------------------------------------------------------------------
// Kernel 2: persistent recurrence, 4B tagged state, WAVE-SPECIALIZED.
//
// 128 WGs x 320 threads. Waves 0-3: compute 4 adjacent rows each (one 16B
// poll group), finalize tanh/leak on lanes 0-3, write own values directly
// into next LDS buffer, lane 0 fires ONE tagged dwordx4 store (fire and
// forget). Wave 4: POLL-ONLY — issues no stores ever, so its s_waitcnt
// vmcnt(0) covers only its own 8 coalesced poll loads (vmcnt decrements in
// order: R5 showed a wave that stores pays the store-ack round trip on its
// next waitcnt — that was the regression). Compute waves' ack waits (from
// the compiler's pre-barrier waitcnt) overlap with wave 4's detection.
//
// State word = fp32 bits, low 2 mantissa bits = (step & 3). Producer skew
// <= 2 steps (producer advances a slot t -> t+2 only after every WG consumed
// s_{t+1}), so mod-4 tags disambiguate; <= 3 ulp value perturbation.
// s_0 is exact zeros -> materialized directly in LDS, never polled.
// One __syncthreads per step for all 5 waves.
// ---------------------------------------------------------------------------
__global__ __launch_bounds__(NTHREADS, 1) void reservoir_kernel(
    const float* __restrict__ W, float* __restrict__ it,
    unsigned int* sbuf) {
  const int wg = blockIdx.x;
  const int tid = threadIdx.x;
  const int wave = tid >> 6;       // 0..4
  const int lane = tid & 63;
  const int R = wg * RPW;

  __shared__ float Wl[RPW * N_RES];   // 128 KB
  __shared__ float ls[2][N_RES];      //  16 KB

  // Stage this WG's 16 W rows into LDS once.
  {
    const float4* Wg = reinterpret_cast<const float4*>(W + (size_t)R * N_RES);
    float4* Wd = reinterpret_cast<float4*>(Wl);
    for (int idx = tid; idx < RPW * N_RES / 4; idx += NTHREADS)
      Wd[idx] = Wg[idx];
  }
  // s_0 = zeros (reset_state=True): no global traffic, just zero LDS.
  for (int idx = tid; idx < N_RES; idx += NTHREADS) ls[0][idx] = 0.f;
  __syncthreads();

  if (wave < 4) {
    // ================= compute waves =================
    const int r0 = R + wave * RPWAVE;
    const float4* W0 = reinterpret_cast<const float4*>(Wl + (size_t)(RPWAVE * wave + 0) * N_RES);
    const float4* W1 = reinterpret_cast<const float4*>(Wl + (size_t)(RPWAVE * wave + 1) * N_RES);
    const float4* W2 = reinterpret_cast<const float4*>(Wl + (size_t)(RPWAVE * wave + 2) * N_RES);
    const float4* W3 = reinterpret_cast<const float4*>(Wl + (size_t)(RPWAVE * wave + 3) * N_RES);

    float itv = 0.f;
    if (lane < RPWAVE) itv = it[r0 + lane];

    for (unsigned int t = 0; t < T_STEPS; ++t) {
      const float* cur = ls[t & 1];
      float* nxt = ls[(t + 1) & 1];
      unsigned int* swb = sbuf + ((t + 1) & 1) * N_RES;

      const float4* S4 = reinterpret_cast<const float4*>(cur);
      float a0 = 0.f, a1 = 0.f, a2 = 0.f, a3 = 0.f;
      #pragma unroll
      for (int j = 0; j < N_RES / 4 / 64; ++j) {
        const float4 s4 = S4[lane + 64 * j];
        const float4 x0 = W0[lane + 64 * j];
        const float4 x1 = W1[lane + 64 * j];
        const float4 x2 = W2[lane + 64 * j];
        const float4 x3 = W3[lane + 64 * j];
        a0 = fmaf(x0.x, s4.x, a0); a0 = fmaf(x0.y, s4.y, a0);
        a0 = fmaf(x0.z, s4.z, a0); a0 = fmaf(x0.w, s4.w, a0);
        a1 = fmaf(x1.x, s4.x, a1); a1 = fmaf(x1.y, s4.y, a1);
        a1 = fmaf(x1.z, s4.z, a1); a1 = fmaf(x1.w, s4.w, a1);
        a2 = fmaf(x2.x, s4.x, a2); a2 = fmaf(x2.y, s4.y, a2);
        a2 = fmaf(x2.z, s4.z, a2); a2 = fmaf(x2.w, s4.w, a2);
        a3 = fmaf(x3.x, s4.x, a3); a3 = fmaf(x3.y, s4.y, a3);
        a3 = fmaf(x3.z, s4.z, a3); a3 = fmaf(x3.w, s4.w, a3);
      }
      #pragma unroll
      for (int off = 32; off > 0; off >>= 1) {
        a0 += __shfl_xor(a0, off);
        a1 += __shfl_xor(a1, off);
        a2 += __shfl_xor(a2, off);
        a3 += __shfl_xor(a3, off);
      }

      const unsigned int tg = (t + 1) & 3u;
      unsigned int pkw = 0;
      if (lane < RPWAVE) {
        const float a = (lane == 0) ? a0 : (lane == 1) ? a1 : (lane == 2) ? a2 : a3;
        const float h = tanhf(itv + a);
        const float sold = cur[r0 + lane];
        const float snew = (1.0f - LEAK) * sold + LEAK * h;
        pkw = (__float_as_uint(snew) & ~3u) | tg;
        // Own value straight into next LDS buffer (tag-masked bits, bit-
        // identical to what remote WGs read) — wave 4 skips own groups.
        nxt[r0 + lane] = __uint_as_float(pkw);
        it[(size_t)t * N_RES + r0 + lane] = snew;  // record state for readout
      }
      // Pack the wave's 4 rows; lane 0 fires one tagged store (never waited).
      uint32x4 pk;
      pk[0] = __shfl(pkw, 0);
      pk[1] = __shfl(pkw, 1);
      pk[2] = __shfl(pkw, 2);
      pk[3] = __shfl(pkw, 3);
      if (lane == 0) {
        uint32x4* dst = reinterpret_cast<uint32x4*>(swb) + (r0 >> 2);
        asm volatile("global_store_dwordx4 %0, %1, off sc0 sc1"
                     :: "v"(dst), "v"(pk) : "memory");
      }
      // Prefetch next input term (ack+load wait overlaps wave 4's detect).
      if (lane < RPWAVE && t + 1 < T_STEPS)
        itv = it[(size_t)(t + 1) * N_RES + r0 + lane];

      __syncthreads();  // nxt complete (own writes + wave-4 remote fills)
    }
  } else {
    // ================= poll wave (wave 4) — NEVER stores =================
    // Lane l owns groups g = l + 64k, k=0..7 (512 groups of 16B). Own WG's
    // 4 groups are filled by compute waves; mask them out.
    unsigned int ownmask = 0;
    {
      const int j = lane - ((wg * 4) & 63);
      if (0 <= j && j < 4) ownmask = 1u << (wg >> 4);
    }
    for (unsigned int t = 0; t < T_STEPS; ++t) {
      if (t + 1 < T_STEPS) {
        unsigned int* swb = sbuf + ((t + 1) & 1) * N_RES;
        float* nxt = ls[(t + 1) & 1];
        const unsigned int tg = (t + 1) & 3u;
        const char* p0 = (const char*)swb + lane * 16;
        const char* p1 = p0 + 4096;
        uint32x4* dst = reinterpret_cast<uint32x4*>(nxt);
        unsigned int need = 0xFFu & ~ownmask;
        for (;;) {
          uint32x4 v0, v1, v2, v3, v4, v5, v6, v7;
          asm volatile(
              "global_load_dwordx4 %0, %8, off sc0 sc1\n\t"
              "global_load_dwordx4 %1, %8, off offset:1024 sc0 sc1\n\t"
              "global_load_dwordx4 %2, %8, off offset:2048 sc0 sc1\n\t"
              "global_load_dwordx4 %3, %8, off offset:3072 sc0 sc1\n\t"
              "global_load_dwordx4 %4, %9, off sc0 sc1\n\t"
              "global_load_dwordx4 %5, %9, off offset:1024 sc0 sc1\n\t"
              "global_load_dwordx4 %6, %9, off offset:2048 sc0 sc1\n\t"
              "global_load_dwordx4 %7, %9, off offset:3072 sc0 sc1\n\t"
              "s_waitcnt vmcnt(0)"
              : "=&v"(v0), "=&v"(v1), "=&v"(v2), "=&v"(v3),
                "=&v"(v4), "=&v"(v5), "=&v"(v6), "=&v"(v7)
              : "v"(p0), "v"(p1)
              : "memory");
          if ((need & 1u)   && ((((v0[0]^tg)|(v0[1]^tg)|(v0[2]^tg)|(v0[3]^tg))&3u)==0u)) { dst[lane +   0] = v0; need &= ~1u; }
          if ((need & 2u)   && ((((v1[0]^tg)|(v1[1]^tg)|(v1[2]^tg)|(v1[3]^tg))&3u)==0u)) { dst[lane +  64] = v1; need &= ~2u; }
          if ((need & 4u)   && ((((v2[0]^tg)|(v2[1]^tg)|(v2[2]^tg)|(v2[3]^tg))&3u)==0u)) { dst[lane + 128] = v2; need &= ~4u; }
          if ((need & 8u)   && ((((v3[0]^tg)|(v3[1]^tg)|(v3[2]^tg)|(v3[3]^tg))&3u)==0u)) { dst[lane + 192] = v3; need &= ~8u; }
          if ((need & 16u)  && ((((v4[0]^tg)|(v4[1]^tg)|(v4[2]^tg)|(v4[3]^tg))&3u)==0u)) { dst[lane + 256] = v4; need &= ~16u; }
          if ((need & 32u)  && ((((v5[0]^tg)|(v5[1]^tg)|(v5[2]^tg)|(v5[3]^tg))&3u)==0u)) { dst[lane + 320] = v5; need &= ~32u; }
          if ((need & 64u)  && ((((v6[0]^tg)|(v6[1]^tg)|(v6[2]^tg)|(v6[3]^tg))&3u)==0u)) { dst[lane + 384] = v6; need &= ~64u; }
          if ((need & 128u) && ((((v7[0]^tg)|(v7[1]^tg)|(v7[2]^tg)|(v7[3]^tg))&3u)==0u)) { dst[lane + 448] = v7; need &= ~128u; }
          if (__all(need == 0u)) break;
          __builtin_amdgcn_s_sleep(1);
        }
      }
      __syncthreads();
    }
  }
}

// ---------------------------------------------------------------------------
// Kernel 3: out[t][o] = dot(states[t,:], rw[o,:]) + rb[o]
// ---------------------------------------------------------------------------
__global__ __launch_bounds__(256) void readout_kernel(
    const float* __restrict__ states, const float* __restrict__ rw,
    const float* __restrict__ rb, float* __restrict__ out) {
  const int t = blockIdx.x;
  const int tid = threadIdx.x;
  const int o = tid & 63;
  const int q = tid >> 6;  // 0..3
  __shared__ float ss[N_RES];
  #pragma unroll
  for (int k = 0; k < N_RES / 256; ++k)
    ss[tid + 256 * k] = states[(size_t)t * N_RES + tid + 256 * k];
  __syncthreads();

  const float4* r4 = reinterpret_cast<const float4*>(rw + (size_t)o * N_RES + q * 512);
  float acc = 0.f;
  #pragma unroll 8
  for (int j = 0; j < 128; ++j) {
    float4 w4 = r4[j];
    const int base = q * 512 + 4 * j;
    acc = fmaf(w4.x, ss[base + 0], acc);
    acc = fmaf(w4.y, ss[base + 1], acc);
    acc = fmaf(w4.z, ss[base + 2], acc);
    acc = fmaf(w4.w, ss[base + 3], acc);
  }
  __shared__ float red[256];
  red[tid] = acc;
  __syncthreads();
  if (tid < 64) {
    float v = red[tid] + red[tid + 64] + red[tid + 128] + red[tid + 192];
    out[(size_t)t * N_OUT + tid] = v + rb[tid];
  }
}

// ---------------------------------------------------------------------------
extern "C" void kernel_launch(void* const* d_in, const int* in_sizes, int n_in,
                              void* d_out, int out_size, void* d_ws, size_t ws_size,
                              hipStream_t stream) {
  const float* u     = (const float*)d_in[0];  // [4096, 64]
  const float* noise = (const float*)d_in[1];  // [4096, 2048]
  const float* W_in  = (const float*)d_in[2];  // [2048, 64]
  const float* W     = (const float*)d_in[3];  // [2048, 2048]
  const float* rw    = (const float*)d_in[4];  // [64, 2048]
  const float* rb    = (const float*)d_in[5];  // [64]
  float* out = (float*)d_out;                  // [4096, 64]

  float* it = (float*)d_ws;  // 32 MB: input terms, overwritten with states
  unsigned int* sbuf =
      (unsigned int*)((char*)d_ws + (size_t)T_STEPS * N_RES * sizeof(float));

  // Zero both tagged state buffers every call: first-ever call sees 0xAA
  // poison (tag bits 2 would falsely match step tags); zeros are safe for
  // every step (stale tag = fresh-2 mod 4, never equal).
  hipMemsetAsync(sbuf, 0, 2 * N_RES * sizeof(unsigned int), stream);

  input_terms_kernel<<<T_STEPS, 256, 0, stream>>>(u, noise, W_in, it);

  void* args[] = {(void*)&W, (void*)&it, (void*)&sbuf};
  hipLaunchCooperativeKernel((void*)reservoir_kernel, dim3(NWG), dim3(NTHREADS),
                             args, 0, stream);

  readout_kernel<<<T_STEPS, 256, 0, stream>>>(it, rw, rb, out);
}